// Round 8
// baseline (3225.046 us; speedup 1.0000x reference)
//
#include <hip/hip_runtime.h>

#define TT   512
#define IDIM 64
#define HDIM 256

typedef short  short8  __attribute__((ext_vector_type(8)));
typedef short  short4v __attribute__((ext_vector_type(4)));
typedef float  f32x4   __attribute__((ext_vector_type(4)));
typedef unsigned long long u64;

__device__ __forceinline__ short f2bf(float f) {
    unsigned u = __float_as_uint(f);
    u = u + 0x7FFFu + ((u >> 16) & 1u);   // round-to-nearest-even
    return (short)(u >> 16);
}
__device__ __forceinline__ float bf2f(short h) {
    return __uint_as_float(((unsigned)(unsigned short)h) << 16);
}
__device__ __forceinline__ float sigm(float x)  { return 1.0f / (1.0f + __expf(-x)); }
__device__ __forceinline__ float tanh_(float x) { return 2.0f / (1.0f + __expf(-2.0f * x)) - 1.0f; }

// Unpack 16 bf16 units from 6 seq-tagged words: word w = [u(3w) u(3w+1) u(3w+2) seq]
__device__ __forceinline__ void unpack16(const u64 W[6], u64 q[4]) {
    unsigned short u[16];
#pragma unroll
    for (int w = 0; w < 6; ++w)
#pragma unroll
        for (int k = 0; k < 3; ++k) {
            int j = 3 * w + k;
            if (j < 16) u[j] = (unsigned short)(W[w] >> (16 * k));
        }
#pragma unroll
    for (int t = 0; t < 4; ++t)
        q[t] = (u64)u[4*t] | ((u64)u[4*t+1] << 16) | ((u64)u[4*t+2] << 32) | ((u64)u[4*t+3] << 48);
}

// 256 persistent workgroups = 16 batch-groups (grp, 16 rows) x 16 hidden-chunks
// (r6 geometry — best verified). Exchange protocol = r5/r6 PROVEN, unchanged:
// word = [3 bf16 | seq16], seq = s+1; agent-scope swap publish; readers poll the
// tags (each word self-certifies — no flags, no acks, no ordering requirements);
// 2 regions (parity s&1); recycle-safe (publish s only after s-1 gather barrier);
// poll budget => hang-proof.
// Round-8 changes (intra-step latency only, protocol untouched):
//  1. shuffle-pack publish: h words are packed from 3 ADJACENT LANES via
//     __shfl_down — the hls LDS staging buffer and its barrier are deleted;
//     publish issues directly from the cell phase (3 barriers/step -> 2).
//  2. 2-deep pipelined poll: issue batch B / check batch A / issue A / check B,
//     latching per-word (tags make mixed-batch assembly sound). One batch is
//     always in flight while the other is checked -> detect granularity drops
//     from a full MALL round trip to the loop-body time. Reissue only missing
//     words (traffic <= r6).
__global__ __launch_bounds__(256, 1) void lstm_fused(
    const float* __restrict__ x,
    const float* __restrict__ Wih0, const float* __restrict__ Whh0,
    const float* __restrict__ bih0, const float* __restrict__ bhh0,
    const float* __restrict__ Wih1, const float* __restrict__ Whh1,
    const float* __restrict__ bih1, const float* __restrict__ bhh1,
    const float* __restrict__ Wfc,  const float* __restrict__ bfc,
    float* __restrict__ out, char* __restrict__ ws)
{
    u64* h0buf = (u64*)ws;                    // [2][16][16][96] seq-tagged words
    u64* h1buf = h0buf + 2 * 16 * 16 * 96;    // [2][16][16][96]
    // total = 768 KiB (< proven 1 MiB ws capacity)

    const int blk   = blockIdx.x;
    const int grp   = ((blk & 7) << 1) | ((blk >> 3) & 1); // batch-group 0..15
    const int chunk = blk >> 4;                            // hidden-chunk 0..15
    const int tid   = threadIdx.x;
    const int lane  = tid & 63;
    const int wave  = tid >> 6;      // gate index: 0=i 1=f 2=g 3=o
    const int quad  = lane >> 4;
    const int nn    = lane & 15;     // W-row within 16-row tile

    __shared__ short A0[16][328];    // [m][ x(64) | h0(256) ] + pad
    __shared__ short A1[16][520];    // [m][ h0(256) | h1(256) ] + pad
    __shared__ float gbuf[2][4][16][16];
    __shared__ float red[16][16];
    __shared__ float ldspad[5120];   // occupancy limiter: ~57 KB -> 1 wg/CU

    // zero A buffers (h0[-1] = 0, h1[-1] = 0 for the s==1 layer1 step)
    for (int i = tid; i < 16 * 328; i += 256) (&A0[0][0])[i] = 0;
    for (int i = tid; i < 16 * 520; i += 256) (&A1[0][0])[i] = 0;

    // ---- static weight fragments -> registers (B operand: W[n][k], n=lane&15, k=quad*8+j)
    const int wrow = wave * HDIM + chunk * 16 + nn;
    short8 w0f[10];   // layer0: kb 0..1 = Wih0 (K 0..63), kb 2..9 = Whh0 (K 64..319)
    short8 w1f[16];   // layer1: kb 0..7 = Wih1 (K 0..255), kb 8..15 = Whh1 (K 256..511)
#pragma unroll
    for (int kb = 0; kb < 10; ++kb)
#pragma unroll
        for (int j = 0; j < 8; ++j) {
            int k = kb * 32 + quad * 8 + j;
            float v = (k < 64) ? Wih0[wrow * IDIM + k] : Whh0[wrow * HDIM + (k - 64)];
            w0f[kb][j] = f2bf(v);
        }
#pragma unroll
    for (int kb = 0; kb < 16; ++kb)
#pragma unroll
        for (int j = 0; j < 8; ++j) {
            int k = kb * 32 + quad * 8 + j;
            float v = (k < 256) ? Wih1[wrow * HDIM + k] : Whh1[wrow * HDIM + (k - 256)];
            w1f[kb][j] = f2bf(v);
        }
    const float bias0 = bih0[wrow] + bhh0[wrow];
    const float bias1 = bih1[wrow] + bhh1[wrow];

    const int em = tid >> 4;   // elementwise batch row (0..15)
    const int ej = tid & 15;   // elementwise hidden unit within chunk / gather chunk
    float c0 = 0.0f, c1 = 0.0f;

    auto load_x = [&](int t) {
        const float4 v = *(const float4*)&x[((size_t)(grp * 16 + em) * TT + t) * IDIM + ej * 4];
        short4v sv;
        sv[0] = f2bf(v.x); sv[1] = f2bf(v.y); sv[2] = f2bf(v.z); sv[3] = f2bf(v.w);
        *(short4v*)&A0[em][ej * 4] = sv;
    };

    __syncthreads();
    load_x(0);
    __syncthreads();

    // super-step s: layer0 computes h0[s] (s<T); layer1 computes h1[s-1] (s>=1)
    for (int s = 0; s <= TT; ++s) {
        if (s < TT) {
            f32x4 accA = {0.f, 0.f, 0.f, 0.f}, accB = {0.f, 0.f, 0.f, 0.f};
#pragma unroll
            for (int kb = 0; kb < 10; kb += 2) {   // 2 chains: halve dep latency
                short8 a0v = *(const short8*)&A0[nn][kb * 32 + quad * 8];
                short8 a1v = *(const short8*)&A0[nn][(kb + 1) * 32 + quad * 8];
                accA = __builtin_amdgcn_mfma_f32_16x16x32_bf16(a0v, w0f[kb],     accA, 0, 0, 0);
                accB = __builtin_amdgcn_mfma_f32_16x16x32_bf16(a1v, w0f[kb + 1], accB, 0, 0, 0);
            }
            const f32x4 acc = accA + accB;
#pragma unroll
            for (int r = 0; r < 4; ++r)
                gbuf[0][wave][quad * 4 + r][nn] = acc[r] + bias0;
        }
        if (s >= 1) {
            f32x4 accA = {0.f, 0.f, 0.f, 0.f}, accB = {0.f, 0.f, 0.f, 0.f};
#pragma unroll
            for (int kb = 0; kb < 16; kb += 2) {
                short8 a0v = *(const short8*)&A1[nn][kb * 32 + quad * 8];
                short8 a1v = *(const short8*)&A1[nn][(kb + 1) * 32 + quad * 8];
                accA = __builtin_amdgcn_mfma_f32_16x16x32_bf16(a0v, w1f[kb],     accA, 0, 0, 0);
                accB = __builtin_amdgcn_mfma_f32_16x16x32_bf16(a1v, w1f[kb + 1], accB, 0, 0, 0);
            }
            const f32x4 acc = accA + accB;
#pragma unroll
            for (int r = 0; r < 4; ++r)
                gbuf[1][wave][quad * 4 + r][nn] = acc[r] + bias1;
        }
        __syncthreads();

        // ---- cell updates + shuffle-pack publish (no staging barrier).
        // Thread (em,ej): rows are 16-lane groups, so units ej+1, ej+2 are lanes
        // lane+1, lane+2 of the same wave -> __shfl_down. Publishers ej%3==0
        // pack word w=ej/3 = [3 units | seq] and swap-publish both buffers.
        {
            short h0v = 0, h1v = 0;
            if (s < TT) {
                float gi = sigm (gbuf[0][0][em][ej]);
                float gf = sigm (gbuf[0][1][em][ej]);
                float gg = tanh_(gbuf[0][2][em][ej]);
                float go = sigm (gbuf[0][3][em][ej]);
                c0 = gf * c0 + gi * gg;
                h0v = f2bf(go * tanh_(c0));
            }
            if (s >= 1) {
                float gi = sigm (gbuf[1][0][em][ej]);
                float gf = sigm (gbuf[1][1][em][ej]);
                float gg = tanh_(gbuf[1][2][em][ej]);
                float go = sigm (gbuf[1][3][em][ej]);
                c1 = gf * c1 + gi * gg;
                h1v = f2bf(go * tanh_(c1));
            }
            const int hv = (int)(unsigned short)h0v | ((int)(unsigned short)h1v << 16);
            const int n1 = __shfl_down(hv, 1);
            const int n2 = __shfl_down(hv, 2);
            if ((ej % 3) == 0) {
                const int w = ej / 3;          // 0..5 (w=5: single unit 15)
                u64 v0 = (u64)(unsigned)(s + 1) << 48;
                u64 v1 = v0;
                v0 |= (u64)(unsigned)(hv & 0xFFFF);
                v1 |= (u64)((unsigned)hv >> 16);
                if (w < 5) {
                    v0 |= (u64)(unsigned)(n1 & 0xFFFF) << 16;
                    v1 |= (u64)((unsigned)n1 >> 16) << 16;
                    v0 |= (u64)(unsigned)(n2 & 0xFFFF) << 32;
                    v1 |= (u64)((unsigned)n2 >> 16) << 32;
                }
                const size_t base = (((size_t)(s & 1) * 16 + grp) * 16 + em) * 96
                                    + chunk * 6 + w;
                (void)__hip_atomic_exchange(&h0buf[base], v0,
                                            __ATOMIC_RELAXED, __HIP_MEMORY_SCOPE_AGENT);
                (void)__hip_atomic_exchange(&h1buf[base], v1,
                                            __ATOMIC_RELAXED, __HIP_MEMORY_SCOPE_AGENT);
            }
        }

        if (s + 1 < TT) load_x(s + 1);   // overlap x prefetch with the poll

        // ---- 2-deep pipelined seq-poll + gather (poll result IS the data).
        // One batch always in flight while the other is checked; per-word latch.
        {
            const bool g0 = (s < TT), g1 = (s >= 1);
            const unsigned sq = (unsigned)(s + 1);
            const size_t rb = (((size_t)(s & 1) * 16 + grp) * 16 + em) * 96 + ej * 6;
            const u64* p0 = h0buf + rb;
            const u64* p1 = h1buf + rb;
            u64 R0[6], R1[6];
            bool got0[6], got1[6];
#pragma unroll
            for (int i = 0; i < 6; ++i) { got0[i] = !g0; got1[i] = !g1; R0[i] = 0; R1[i] = 0; }
            bool all = !g0 && !g1;
            int budget = 1 << 16;   // hang-proofing: exhaust -> finite absmax fail
            if (!all) {
                u64 Aw0[6], Aw1[6], Bw0[6], Bw1[6];
#pragma unroll
                for (int i = 0; i < 6; ++i)
                    Aw0[i] = g0 ? __hip_atomic_load(p0 + i, __ATOMIC_RELAXED,
                                                    __HIP_MEMORY_SCOPE_AGENT) : 0;
#pragma unroll
                for (int i = 0; i < 6; ++i)
                    Aw1[i] = g1 ? __hip_atomic_load(p1 + i, __ATOMIC_RELAXED,
                                                    __HIP_MEMORY_SCOPE_AGENT) : 0;
                for (;;) {
                    // issue B (missing words only)
#pragma unroll
                    for (int i = 0; i < 6; ++i)
                        Bw0[i] = got0[i] ? 0 : __hip_atomic_load(p0 + i, __ATOMIC_RELAXED,
                                                                 __HIP_MEMORY_SCOPE_AGENT);
#pragma unroll
                    for (int i = 0; i < 6; ++i)
                        Bw1[i] = got1[i] ? 0 : __hip_atomic_load(p1 + i, __ATOMIC_RELAXED,
                                                                 __HIP_MEMORY_SCOPE_AGENT);
                    // check A (B stays in flight)
                    all = true;
#pragma unroll
                    for (int i = 0; i < 6; ++i) {
                        if (!got0[i]) {
                            if ((unsigned)(Aw0[i] >> 48) == sq) { R0[i] = Aw0[i]; got0[i] = true; }
                            else all = false;
                        }
                        if (!got1[i]) {
                            if ((unsigned)(Aw1[i] >> 48) == sq) { R1[i] = Aw1[i]; got1[i] = true; }
                            else all = false;
                        }
                    }
                    if (all || --budget < 0) break;
                    // issue A (missing words only)
#pragma unroll
                    for (int i = 0; i < 6; ++i)
                        Aw0[i] = got0[i] ? 0 : __hip_atomic_load(p0 + i, __ATOMIC_RELAXED,
                                                                 __HIP_MEMORY_SCOPE_AGENT);
#pragma unroll
                    for (int i = 0; i < 6; ++i)
                        Aw1[i] = got1[i] ? 0 : __hip_atomic_load(p1 + i, __ATOMIC_RELAXED,
                                                                 __HIP_MEMORY_SCOPE_AGENT);
                    // check B (A stays in flight)
                    all = true;
#pragma unroll
                    for (int i = 0; i < 6; ++i) {
                        if (!got0[i]) {
                            if ((unsigned)(Bw0[i] >> 48) == sq) { R0[i] = Bw0[i]; got0[i] = true; }
                            else all = false;
                        }
                        if (!got1[i]) {
                            if ((unsigned)(Bw1[i] >> 48) == sq) { R1[i] = Bw1[i]; got1[i] = true; }
                            else all = false;
                        }
                    }
                    if (all || --budget < 0) break;
                }
            }
            asm volatile("s_waitcnt vmcnt(0)" ::: "memory");   // drain before region reuse

            if (g0) {
                u64 q[4]; unpack16(R0, q);
                u64* d0 = (u64*)&A0[em][64 + ej * 16];
                u64* d1 = (u64*)&A1[em][ej * 16];
#pragma unroll
                for (int t = 0; t < 4; ++t) { d0[t] = q[t]; d1[t] = q[t]; }
            }
            if (g1) {
                u64 q[4]; unpack16(R1, q);
                u64* d2 = (u64*)&A1[em][256 + ej * 16];
#pragma unroll
                for (int t = 0; t < 4; ++t) d2[t] = q[t];
            }
        }
        __syncthreads();
    }

    // FC epilogue: A1[:,256..511] holds h1[T-1] (bf16)
    {
        float part = 0.f;
#pragma unroll
        for (int kk = 0; kk < 16; ++kk) {
            int k = ej * 16 + kk;
            part += bf2f(A1[em][256 + k]) * Wfc[k];
        }
        red[em][ej] = part;
    }
    __syncthreads();
    if (chunk == 0 && tid < 16) {
        float sum = bfc[0];
#pragma unroll
        for (int c = 0; c < 16; ++c) sum += red[tid][c];
        out[grp * 16 + tid] = sum;
    }

    // keep ldspad allocated (occupancy cap); never true at runtime
    if (gridDim.x > 100000) { ldspad[tid] = bias0; out[0] = ldspad[255 - tid]; }
}

extern "C" void kernel_launch(void* const* d_in, const int* in_sizes, int n_in,
                              void* d_out, int out_size, void* d_ws, size_t ws_size,
                              hipStream_t stream) {
    (void)in_sizes; (void)n_in; (void)out_size; (void)ws_size;
    const float* x    = (const float*)d_in[0];
    const float* Wih0 = (const float*)d_in[1];
    const float* Whh0 = (const float*)d_in[2];
    const float* bih0 = (const float*)d_in[3];
    const float* bhh0 = (const float*)d_in[4];
    const float* Wih1 = (const float*)d_in[5];
    const float* Whh1 = (const float*)d_in[6];
    const float* bih1 = (const float*)d_in[7];
    const float* bhh1 = (const float*)d_in[8];
    const float* Wfc  = (const float*)d_in[9];
    const float* bfc  = (const float*)d_in[10];

    lstm_fused<<<256, 256, 0, stream>>>(x, Wih0, Whh0, bih0, bhh0,
                                        Wih1, Whh1, bih1, bhh1, Wfc, bfc,
                                        (float*)d_out, (char*)d_ws);
}

// Round 9
// 1658.679 us; speedup vs baseline: 1.9443x; 1.9443x over previous
//
#include <hip/hip_runtime.h>

#define TT   512
#define IDIM 64
#define HDIM 256

typedef short  short8  __attribute__((ext_vector_type(8)));
typedef short  short4v __attribute__((ext_vector_type(4)));
typedef float  f32x4   __attribute__((ext_vector_type(4)));
typedef unsigned long long u64;

__device__ __forceinline__ short f2bf(float f) {
    unsigned u = __float_as_uint(f);
    u = u + 0x7FFFu + ((u >> 16) & 1u);   // round-to-nearest-even
    return (short)(u >> 16);
}
__device__ __forceinline__ float bf2f(short h) {
    return __uint_as_float(((unsigned)(unsigned short)h) << 16);
}
__device__ __forceinline__ float sigm(float x)  { return 1.0f / (1.0f + __expf(-x)); }
__device__ __forceinline__ float tanh_(float x) { return 2.0f / (1.0f + __expf(-2.0f * x)) - 1.0f; }

// Unpack 16 bf16 units from 6 seq-tagged words: word w = [u(3w) u(3w+1) u(3w+2) seq]
__device__ __forceinline__ void unpack16(const u64 W[6], u64 q[4]) {
    unsigned short u[16];
#pragma unroll
    for (int w = 0; w < 6; ++w)
#pragma unroll
        for (int k = 0; k < 3; ++k) {
            int j = 3 * w + k;
            if (j < 16) u[j] = (unsigned short)(W[w] >> (16 * k));
        }
#pragma unroll
    for (int t = 0; t < 4; ++t)
        q[t] = (u64)u[4*t] | ((u64)u[4*t+1] << 16) | ((u64)u[4*t+2] << 32) | ((u64)u[4*t+3] << 48);
}

// 256 persistent workgroups = 16 batch-groups (grp, 16 rows) x 16 hidden-chunks
// (r6 geometry — best verified, 1789us). Exchange protocol = r5/r6 PROVEN,
// unchanged: word = [3 bf16 | seq16], seq = s+1; agent-scope swap publish;
// readers poll tags (each word self-certifies — no flags, no acks, no ordering
// requirements); 2 regions (parity s&1); recycle-safe (publish s only after the
// s-1 gather barrier); poll budget => hang-proof. Poll = r6 single-batch form
// (r8's 2-deep poll doubled MALL traffic -> regression + outliers; reverted).
// Round-9 change (phase reorder ONLY): publish h0 IMMEDIATELY after cell0 via
// shuffle-pack (r8-proven correct), then run MFMA1+cell1 INSIDE h0's
// publish->visibility window instead of before the publish. Hoists ~0.3-0.4us
// of layer1 compute off the h0 recurrence critical chain. h1 publishes later,
// but its consumer (next step's MFMA1) also runs later by the same amount.
// Barriers still 3/step; hazards: gbuf0 (bar1), A1-read-vs-gather-write (bar2),
// A/gbuf reuse (bar3).
__global__ __launch_bounds__(256, 1) void lstm_fused(
    const float* __restrict__ x,
    const float* __restrict__ Wih0, const float* __restrict__ Whh0,
    const float* __restrict__ bih0, const float* __restrict__ bhh0,
    const float* __restrict__ Wih1, const float* __restrict__ Whh1,
    const float* __restrict__ bih1, const float* __restrict__ bhh1,
    const float* __restrict__ Wfc,  const float* __restrict__ bfc,
    float* __restrict__ out, char* __restrict__ ws)
{
    u64* h0buf = (u64*)ws;                    // [2][16][16][96] seq-tagged words
    u64* h1buf = h0buf + 2 * 16 * 16 * 96;    // [2][16][16][96]
    // total = 768 KiB (< proven 1 MiB ws capacity)

    const int blk   = blockIdx.x;
    const int grp   = ((blk & 7) << 1) | ((blk >> 3) & 1); // batch-group 0..15
    const int chunk = blk >> 4;                            // hidden-chunk 0..15
    const int tid   = threadIdx.x;
    const int lane  = tid & 63;
    const int wave  = tid >> 6;      // gate index: 0=i 1=f 2=g 3=o
    const int quad  = lane >> 4;
    const int nn    = lane & 15;     // W-row within 16-row tile

    __shared__ short A0[16][328];    // [m][ x(64) | h0(256) ] + pad
    __shared__ short A1[16][520];    // [m][ h0(256) | h1(256) ] + pad
    __shared__ float gbuf[2][4][16][17];  // row pad: de-alias gate-write banks
    __shared__ float red[16][16];
    __shared__ float ldspad[5120];   // occupancy limiter: ~57 KB -> 1 wg/CU

    // zero A buffers (h0[-1] = 0, h1[-1] = 0 for the s==1 layer1 step)
    for (int i = tid; i < 16 * 328; i += 256) (&A0[0][0])[i] = 0;
    for (int i = tid; i < 16 * 520; i += 256) (&A1[0][0])[i] = 0;

    // ---- static weight fragments -> registers (B operand: W[n][k], n=lane&15, k=quad*8+j)
    const int wrow = wave * HDIM + chunk * 16 + nn;
    short8 w0f[10];   // layer0: kb 0..1 = Wih0 (K 0..63), kb 2..9 = Whh0 (K 64..319)
    short8 w1f[16];   // layer1: kb 0..7 = Wih1 (K 0..255), kb 8..15 = Whh1 (K 256..511)
#pragma unroll
    for (int kb = 0; kb < 10; ++kb)
#pragma unroll
        for (int j = 0; j < 8; ++j) {
            int k = kb * 32 + quad * 8 + j;
            float v = (k < 64) ? Wih0[wrow * IDIM + k] : Whh0[wrow * HDIM + (k - 64)];
            w0f[kb][j] = f2bf(v);
        }
#pragma unroll
    for (int kb = 0; kb < 16; ++kb)
#pragma unroll
        for (int j = 0; j < 8; ++j) {
            int k = kb * 32 + quad * 8 + j;
            float v = (k < 256) ? Wih1[wrow * HDIM + k] : Whh1[wrow * HDIM + (k - 256)];
            w1f[kb][j] = f2bf(v);
        }
    const float bias0 = bih0[wrow] + bhh0[wrow];
    const float bias1 = bih1[wrow] + bhh1[wrow];

    const int em = tid >> 4;   // elementwise batch row (0..15)
    const int ej = tid & 15;   // elementwise hidden unit within chunk / gather chunk
    float c0 = 0.0f, c1 = 0.0f;

    auto load_x = [&](int t) {
        const float4 v = *(const float4*)&x[((size_t)(grp * 16 + em) * TT + t) * IDIM + ej * 4];
        short4v sv;
        sv[0] = f2bf(v.x); sv[1] = f2bf(v.y); sv[2] = f2bf(v.z); sv[3] = f2bf(v.w);
        *(short4v*)&A0[em][ej * 4] = sv;
    };

    __syncthreads();
    load_x(0);
    __syncthreads();

    // super-step s: layer0 computes h0[s] (s<T); layer1 computes h1[s-1] (s>=1)
    for (int s = 0; s <= TT; ++s) {
        // ---- phase 1: MFMA0 (layer0 gates from A0 = [x[s] | h0[s-1]])
        if (s < TT) {
            f32x4 accA = {0.f, 0.f, 0.f, 0.f}, accB = {0.f, 0.f, 0.f, 0.f};
#pragma unroll
            for (int kb = 0; kb < 10; kb += 2) {   // 2 chains: halve dep latency
                short8 a0v = *(const short8*)&A0[nn][kb * 32 + quad * 8];
                short8 a1v = *(const short8*)&A0[nn][(kb + 1) * 32 + quad * 8];
                accA = __builtin_amdgcn_mfma_f32_16x16x32_bf16(a0v, w0f[kb],     accA, 0, 0, 0);
                accB = __builtin_amdgcn_mfma_f32_16x16x32_bf16(a1v, w0f[kb + 1], accB, 0, 0, 0);
            }
            const f32x4 acc = accA + accB;
#pragma unroll
            for (int r = 0; r < 4; ++r)
                gbuf[0][wave][quad * 4 + r][nn] = acc[r] + bias0;
        }
        __syncthreads();   // gbuf0 complete

        // ---- phase 3: cell0 + IMMEDIATE shuffle-pack publish of h0[s]
        // (r8-proven packing: units ej+1, ej+2 are lanes lane+1, lane+2)
        if (s < TT) {
            float gi = sigm (gbuf[0][0][em][ej]);
            float gf = sigm (gbuf[0][1][em][ej]);
            float gg = tanh_(gbuf[0][2][em][ej]);
            float go = sigm (gbuf[0][3][em][ej]);
            c0 = gf * c0 + gi * gg;
            const short h0v = f2bf(go * tanh_(c0));
            const int hv = (int)(unsigned short)h0v;
            const int n1 = __shfl_down(hv, 1);
            const int n2 = __shfl_down(hv, 2);
            if ((ej % 3) == 0) {
                const int w = ej / 3;          // 0..5 (w=5: single unit 15)
                u64 v0 = (u64)(unsigned)(s + 1) << 48;
                v0 |= (u64)(unsigned)hv;
                if (w < 5) {
                    v0 |= (u64)(unsigned)n1 << 16;
                    v0 |= (u64)(unsigned)n2 << 32;
                }
                const size_t base = (((size_t)(s & 1) * 16 + grp) * 16 + em) * 96
                                    + chunk * 6 + w;
                (void)__hip_atomic_exchange(&h0buf[base], v0,
                                            __ATOMIC_RELAXED, __HIP_MEMORY_SCOPE_AGENT);
            }
        }

        // ---- phase 4: MFMA1 runs INSIDE h0's visibility window
        // (A1 = [h0[s-1] | h1[s-2]] — stable: gather writes happen after bar2)
        if (s >= 1) {
            f32x4 accA = {0.f, 0.f, 0.f, 0.f}, accB = {0.f, 0.f, 0.f, 0.f};
#pragma unroll
            for (int kb = 0; kb < 16; kb += 2) {
                short8 a0v = *(const short8*)&A1[nn][kb * 32 + quad * 8];
                short8 a1v = *(const short8*)&A1[nn][(kb + 1) * 32 + quad * 8];
                accA = __builtin_amdgcn_mfma_f32_16x16x32_bf16(a0v, w1f[kb],     accA, 0, 0, 0);
                accB = __builtin_amdgcn_mfma_f32_16x16x32_bf16(a1v, w1f[kb + 1], accB, 0, 0, 0);
            }
            const f32x4 acc = accA + accB;
#pragma unroll
            for (int r = 0; r < 4; ++r)
                gbuf[1][wave][quad * 4 + r][nn] = acc[r] + bias1;
        }
        __syncthreads();   // gbuf1 complete; all MFMA1 A1-reads done

        // ---- phase 6: cell1 + publish h1[s-1] (zeros at s==0, tag s+1 — never read)
        {
            short h1v = 0;
            if (s >= 1) {
                float gi = sigm (gbuf[1][0][em][ej]);
                float gf = sigm (gbuf[1][1][em][ej]);
                float gg = tanh_(gbuf[1][2][em][ej]);
                float go = sigm (gbuf[1][3][em][ej]);
                c1 = gf * c1 + gi * gg;
                h1v = f2bf(go * tanh_(c1));
            }
            const int hv = (int)(unsigned short)h1v;
            const int n1 = __shfl_down(hv, 1);
            const int n2 = __shfl_down(hv, 2);
            if ((ej % 3) == 0) {
                const int w = ej / 3;
                u64 v1 = (u64)(unsigned)(s + 1) << 48;
                v1 |= (u64)(unsigned)hv;
                if (w < 5) {
                    v1 |= (u64)(unsigned)n1 << 16;
                    v1 |= (u64)(unsigned)n2 << 32;
                }
                const size_t base = (((size_t)(s & 1) * 16 + grp) * 16 + em) * 96
                                    + chunk * 6 + w;
                (void)__hip_atomic_exchange(&h1buf[base], v1,
                                            __ATOMIC_RELAXED, __HIP_MEMORY_SCOPE_AGENT);
            }
        }

        if (s + 1 < TT) load_x(s + 1);   // overlap x prefetch with the poll

        // ---- phase 8: seq-poll + gather (r6 single-batch form, proven)
        {
            const bool g0 = (s < TT), g1 = (s >= 1);
            const unsigned sq = (unsigned)(s + 1);
            const size_t rb = (((size_t)(s & 1) * 16 + grp) * 16 + em) * 96 + ej * 6;
            u64 W0[6], W1[6];
            bool ok0 = !g0, ok1 = !g1;
            int budget = 1 << 17;   // hang-proofing: exhaust -> finite absmax fail
            while ((!ok0 || !ok1) && budget-- > 0) {
                if (!ok0) {
#pragma unroll
                    for (int i = 0; i < 6; ++i)
                        W0[i] = __hip_atomic_load(&h0buf[rb + i],
                                                  __ATOMIC_RELAXED, __HIP_MEMORY_SCOPE_AGENT);
                    bool t = true;
#pragma unroll
                    for (int i = 0; i < 6; ++i) t &= ((unsigned)(W0[i] >> 48) == sq);
                    ok0 = t;
                }
                if (!ok1) {
#pragma unroll
                    for (int i = 0; i < 6; ++i)
                        W1[i] = __hip_atomic_load(&h1buf[rb + i],
                                                  __ATOMIC_RELAXED, __HIP_MEMORY_SCOPE_AGENT);
                    bool t = true;
#pragma unroll
                    for (int i = 0; i < 6; ++i) t &= ((unsigned)(W1[i] >> 48) == sq);
                    ok1 = t;
                }
            }
            // drain: publishes/polls retired before next region reuse
            asm volatile("s_waitcnt vmcnt(0)" ::: "memory");

            if (g0) {
                u64 q[4]; unpack16(W0, q);
                u64* d0 = (u64*)&A0[em][64 + ej * 16];
                u64* d1 = (u64*)&A1[em][ej * 16];
#pragma unroll
                for (int t = 0; t < 4; ++t) { d0[t] = q[t]; d1[t] = q[t]; }
            }
            if (g1) {
                u64 q[4]; unpack16(W1, q);
                u64* d2 = (u64*)&A1[em][256 + ej * 16];
#pragma unroll
                for (int t = 0; t < 4; ++t) d2[t] = q[t];
            }
        }
        __syncthreads();
    }

    // FC epilogue: A1[:,256..511] holds h1[T-1] (bf16)
    {
        float part = 0.f;
#pragma unroll
        for (int kk = 0; kk < 16; ++kk) {
            int k = ej * 16 + kk;
            part += bf2f(A1[em][256 + k]) * Wfc[k];
        }
        red[em][ej] = part;
    }
    __syncthreads();
    if (chunk == 0 && tid < 16) {
        float sum = bfc[0];
#pragma unroll
        for (int c = 0; c < 16; ++c) sum += red[tid][c];
        out[grp * 16 + tid] = sum;
    }

    // keep ldspad allocated (occupancy cap); never true at runtime
    if (gridDim.x > 100000) { ldspad[tid] = bias0; out[0] = ldspad[255 - tid]; }
}

extern "C" void kernel_launch(void* const* d_in, const int* in_sizes, int n_in,
                              void* d_out, int out_size, void* d_ws, size_t ws_size,
                              hipStream_t stream) {
    (void)in_sizes; (void)n_in; (void)out_size; (void)ws_size;
    const float* x    = (const float*)d_in[0];
    const float* Wih0 = (const float*)d_in[1];
    const float* Whh0 = (const float*)d_in[2];
    const float* bih0 = (const float*)d_in[3];
    const float* bhh0 = (const float*)d_in[4];
    const float* Wih1 = (const float*)d_in[5];
    const float* Whh1 = (const float*)d_in[6];
    const float* bih1 = (const float*)d_in[7];
    const float* bhh1 = (const float*)d_in[8];
    const float* Wfc  = (const float*)d_in[9];
    const float* bfc  = (const float*)d_in[10];

    lstm_fused<<<256, 256, 0, stream>>>(x, Wih0, Whh0, bih0, bhh0,
                                        Wih1, Whh1, bih1, bhh1, Wfc, bfc,
                                        (float*)d_out, (char*)d_ws);
}

// Round 10
// 1622.247 us; speedup vs baseline: 1.9880x; 1.0225x over previous
//
#include <hip/hip_runtime.h>

#define TT   512
#define IDIM 64
#define HDIM 256

typedef short  short8  __attribute__((ext_vector_type(8)));
typedef short  short4v __attribute__((ext_vector_type(4)));
typedef float  f32x4   __attribute__((ext_vector_type(4)));
typedef unsigned long long u64;

__device__ __forceinline__ short f2bf(float f) {
    unsigned u = __float_as_uint(f);
    u = u + 0x7FFFu + ((u >> 16) & 1u);   // round-to-nearest-even
    return (short)(u >> 16);
}
__device__ __forceinline__ float bf2f(short h) {
    return __uint_as_float(((unsigned)(unsigned short)h) << 16);
}
__device__ __forceinline__ float sigm(float x)  { return 1.0f / (1.0f + __expf(-x)); }
__device__ __forceinline__ float tanh_(float x) { return 2.0f / (1.0f + __expf(-2.0f * x)) - 1.0f; }

// Unpack 16 bf16 units from 6 seq-tagged words: word w = [u(3w) u(3w+1) u(3w+2) seq]
__device__ __forceinline__ void unpack16(const u64 W[6], u64 q[4]) {
    unsigned short u[16];
#pragma unroll
    for (int w = 0; w < 6; ++w)
#pragma unroll
        for (int k = 0; k < 3; ++k) {
            int j = 3 * w + k;
            if (j < 16) u[j] = (unsigned short)(W[w] >> (16 * k));
        }
#pragma unroll
    for (int t = 0; t < 4; ++t)
        q[t] = (u64)u[4*t] | ((u64)u[4*t+1] << 16) | ((u64)u[4*t+2] << 32) | ((u64)u[4*t+3] << 48);
}

// 256 persistent workgroups = 16 batch-groups (grp, 16 rows) x 16 hidden-chunks.
// Protocol = r5/r6/r9 PROVEN: word = [3 bf16 | seq16]; agent-scope swap publish;
// readers poll tags (self-certifying words — no flags/acks/ordering needs);
// 2 regions (parity); poll budgets => hang-proof.
// Round-10 change (SPLIT POLL along the dependency structure):
//   h0[s]: published phase 3 -> polled phase 8 (consumer: next step's MFMA0).
//   h1[s-2]: polled at TOP of phase 3 of step s (consumer: THIS step's MFMA1) —
//     published a full ~1us earlier (step s-1 phase 6), so visibility is already
//     paid; loads issued first, cell0+publish-h0 runs under them, then tag-check.
//     New bar1.5 orders the A1[256..] gather-write before MFMA1's reads.
//   Phase-8 poll now waits only on h0's residual visibility (~published 0.7us
//   earlier under MFMA1+cell1), not on h1 published 0.1us earlier. h1[T-1] is
//   gathered by a one-shot final poll before the FC epilogue (off hot path).
// Recycle/deadlock safety (induction on strictly-earlier events): P's step-s
// h1-poll needs all blocks' step-(s-1) phase-6 publishes, each after that
// block's step-(s-1) phase-3 poll completed => overwrites of region (s&1) tags
// (P's step-s phase-6) happen only after all step-(s-1) readers of that region
// finished. Same chain as r5's proof, shifted by the split.
__global__ __launch_bounds__(256, 1) void lstm_fused(
    const float* __restrict__ x,
    const float* __restrict__ Wih0, const float* __restrict__ Whh0,
    const float* __restrict__ bih0, const float* __restrict__ bhh0,
    const float* __restrict__ Wih1, const float* __restrict__ Whh1,
    const float* __restrict__ bih1, const float* __restrict__ bhh1,
    const float* __restrict__ Wfc,  const float* __restrict__ bfc,
    float* __restrict__ out, char* __restrict__ ws)
{
    u64* h0buf = (u64*)ws;                    // [2][16][16][96] seq-tagged words
    u64* h1buf = h0buf + 2 * 16 * 16 * 96;    // [2][16][16][96]
    // total = 768 KiB (< proven 1 MiB ws capacity)

    const int blk   = blockIdx.x;
    const int grp   = ((blk & 7) << 1) | ((blk >> 3) & 1); // batch-group 0..15
    const int chunk = blk >> 4;                            // hidden-chunk 0..15
    const int tid   = threadIdx.x;
    const int lane  = tid & 63;
    const int wave  = tid >> 6;      // gate index: 0=i 1=f 2=g 3=o
    const int quad  = lane >> 4;
    const int nn    = lane & 15;     // W-row within 16-row tile

    __shared__ short A0[16][328];    // [m][ x(64) | h0(256) ] + pad
    __shared__ short A1[16][520];    // [m][ h0(256) | h1(256) ] + pad
    __shared__ float gbuf[2][4][16][17];  // row pad: de-alias gate-write banks
    __shared__ float red[16][16];
    __shared__ float ldspad[5120];   // occupancy limiter: ~57 KB -> 1 wg/CU

    // zero A buffers (h0[-1] = 0, h1[-1] = 0 for the s==1 layer1 step)
    for (int i = tid; i < 16 * 328; i += 256) (&A0[0][0])[i] = 0;
    for (int i = tid; i < 16 * 520; i += 256) (&A1[0][0])[i] = 0;

    // ---- static weight fragments -> registers (B operand: W[n][k], n=lane&15, k=quad*8+j)
    const int wrow = wave * HDIM + chunk * 16 + nn;
    short8 w0f[10];   // layer0: kb 0..1 = Wih0 (K 0..63), kb 2..9 = Whh0 (K 64..319)
    short8 w1f[16];   // layer1: kb 0..7 = Wih1 (K 0..255), kb 8..15 = Whh1 (K 256..511)
#pragma unroll
    for (int kb = 0; kb < 10; ++kb)
#pragma unroll
        for (int j = 0; j < 8; ++j) {
            int k = kb * 32 + quad * 8 + j;
            float v = (k < 64) ? Wih0[wrow * IDIM + k] : Whh0[wrow * HDIM + (k - 64)];
            w0f[kb][j] = f2bf(v);
        }
#pragma unroll
    for (int kb = 0; kb < 16; ++kb)
#pragma unroll
        for (int j = 0; j < 8; ++j) {
            int k = kb * 32 + quad * 8 + j;
            float v = (k < 256) ? Wih1[wrow * HDIM + k] : Whh1[wrow * HDIM + (k - 256)];
            w1f[kb][j] = f2bf(v);
        }
    const float bias0 = bih0[wrow] + bhh0[wrow];
    const float bias1 = bih1[wrow] + bhh1[wrow];

    const int em = tid >> 4;   // elementwise batch row (0..15)
    const int ej = tid & 15;   // elementwise hidden unit within chunk / gather chunk
    float c0 = 0.0f, c1 = 0.0f;

    auto load_x = [&](int t) {
        const float4 v = *(const float4*)&x[((size_t)(grp * 16 + em) * TT + t) * IDIM + ej * 4];
        short4v sv;
        sv[0] = f2bf(v.x); sv[1] = f2bf(v.y); sv[2] = f2bf(v.z); sv[3] = f2bf(v.w);
        *(short4v*)&A0[em][ej * 4] = sv;
    };

    __syncthreads();
    load_x(0);
    __syncthreads();

    // super-step s: layer0 computes h0[s] (s<T); layer1 computes h1[s-1] (s>=1)
    for (int s = 0; s <= TT; ++s) {
        // ---- phase 1: MFMA0 (layer0 gates from A0 = [x[s] | h0[s-1]])
        if (s < TT) {
            f32x4 accA = {0.f, 0.f, 0.f, 0.f}, accB = {0.f, 0.f, 0.f, 0.f};
#pragma unroll
            for (int kb = 0; kb < 10; kb += 2) {   // 2 chains: halve dep latency
                short8 a0v = *(const short8*)&A0[nn][kb * 32 + quad * 8];
                short8 a1v = *(const short8*)&A0[nn][(kb + 1) * 32 + quad * 8];
                accA = __builtin_amdgcn_mfma_f32_16x16x32_bf16(a0v, w0f[kb],     accA, 0, 0, 0);
                accB = __builtin_amdgcn_mfma_f32_16x16x32_bf16(a1v, w0f[kb + 1], accB, 0, 0, 0);
            }
            const f32x4 acc = accA + accB;
#pragma unroll
            for (int r = 0; r < 4; ++r)
                gbuf[0][wave][quad * 4 + r][nn] = acc[r] + bias0;
        }
        __syncthreads();   // bar1: gbuf0 complete

        // ---- phase 3: issue h1[s-2] poll loads -> cell0 + publish h0[s] -> check h1
        {
            const bool gh1 = (s >= 2);
            const unsigned sq1 = (unsigned)s;   // tag of h1[s-2] (published step s-1)
            const size_t rb1 = (((size_t)((s - 1) & 1) * 16 + grp) * 16 + em) * 96 + ej * 6;
            u64 W1[6];
            if (gh1) {
#pragma unroll
                for (int i = 0; i < 6; ++i)     // issue early; fly under cell0
                    W1[i] = __hip_atomic_load(&h1buf[rb1 + i],
                                              __ATOMIC_RELAXED, __HIP_MEMORY_SCOPE_AGENT);
            }

            if (s < TT) {
                float gi = sigm (gbuf[0][0][em][ej]);
                float gf = sigm (gbuf[0][1][em][ej]);
                float gg = tanh_(gbuf[0][2][em][ej]);
                float go = sigm (gbuf[0][3][em][ej]);
                c0 = gf * c0 + gi * gg;
                const short h0v = f2bf(go * tanh_(c0));
                const int hv = (int)(unsigned short)h0v;
                const int n1 = __shfl_down(hv, 1);
                const int n2 = __shfl_down(hv, 2);
                if ((ej % 3) == 0) {
                    const int w = ej / 3;          // 0..5 (w=5: single unit 15)
                    u64 v0 = (u64)(unsigned)(s + 1) << 48;
                    v0 |= (u64)(unsigned)hv;
                    if (w < 5) {
                        v0 |= (u64)(unsigned)n1 << 16;
                        v0 |= (u64)(unsigned)n2 << 32;
                    }
                    const size_t base = (((size_t)(s & 1) * 16 + grp) * 16 + em) * 96
                                        + chunk * 6 + w;
                    (void)__hip_atomic_exchange(&h0buf[base], v0,
                                                __ATOMIC_RELAXED, __HIP_MEMORY_SCOPE_AGENT);
                }
            }

            if (gh1) {
                bool ok = true;
#pragma unroll
                for (int i = 0; i < 6; ++i) ok &= ((unsigned)(W1[i] >> 48) == sq1);
                int budget = 1 << 17;   // expected: already visible -> no spin
                while (!ok && budget-- > 0) {
#pragma unroll
                    for (int i = 0; i < 6; ++i)
                        W1[i] = __hip_atomic_load(&h1buf[rb1 + i],
                                                  __ATOMIC_RELAXED, __HIP_MEMORY_SCOPE_AGENT);
                    ok = true;
#pragma unroll
                    for (int i = 0; i < 6; ++i) ok &= ((unsigned)(W1[i] >> 48) == sq1);
                }
                u64 q[4]; unpack16(W1, q);
                u64* d2 = (u64*)&A1[em][256 + ej * 16];
#pragma unroll
                for (int t = 0; t < 4; ++t) d2[t] = q[t];
            }
        }
        __syncthreads();   // bar1.5: A1 h1-region ready for MFMA1

        // ---- phase 4: MFMA1 (A1 = [h0[s-1] | h1[s-2]]) inside h0's visibility window
        if (s >= 1) {
            f32x4 accA = {0.f, 0.f, 0.f, 0.f}, accB = {0.f, 0.f, 0.f, 0.f};
#pragma unroll
            for (int kb = 0; kb < 16; kb += 2) {
                short8 a0v = *(const short8*)&A1[nn][kb * 32 + quad * 8];
                short8 a1v = *(const short8*)&A1[nn][(kb + 1) * 32 + quad * 8];
                accA = __builtin_amdgcn_mfma_f32_16x16x32_bf16(a0v, w1f[kb],     accA, 0, 0, 0);
                accB = __builtin_amdgcn_mfma_f32_16x16x32_bf16(a1v, w1f[kb + 1], accB, 0, 0, 0);
            }
            const f32x4 acc = accA + accB;
#pragma unroll
            for (int r = 0; r < 4; ++r)
                gbuf[1][wave][quad * 4 + r][nn] = acc[r] + bias1;
        }
        __syncthreads();   // bar2: gbuf1 complete; all MFMA1 A1-reads done

        // ---- phase 6: cell1 + publish h1[s-1] (zeros at s==0; tag never polled)
        {
            short h1v = 0;
            if (s >= 1) {
                float gi = sigm (gbuf[1][0][em][ej]);
                float gf = sigm (gbuf[1][1][em][ej]);
                float gg = tanh_(gbuf[1][2][em][ej]);
                float go = sigm (gbuf[1][3][em][ej]);
                c1 = gf * c1 + gi * gg;
                h1v = f2bf(go * tanh_(c1));
            }
            const int hv = (int)(unsigned short)h1v;
            const int n1 = __shfl_down(hv, 1);
            const int n2 = __shfl_down(hv, 2);
            if ((ej % 3) == 0) {
                const int w = ej / 3;
                u64 v1 = (u64)(unsigned)(s + 1) << 48;
                v1 |= (u64)(unsigned)hv;
                if (w < 5) {
                    v1 |= (u64)(unsigned)n1 << 16;
                    v1 |= (u64)(unsigned)n2 << 32;
                }
                const size_t base = (((size_t)(s & 1) * 16 + grp) * 16 + em) * 96
                                    + chunk * 6 + w;
                (void)__hip_atomic_exchange(&h1buf[base], v1,
                                            __ATOMIC_RELAXED, __HIP_MEMORY_SCOPE_AGENT);
            }
        }

        if (s + 1 < TT) load_x(s + 1);   // overlap x prefetch with the poll

        // ---- phase 8: poll h0[s] ONLY + gather (r6 single-batch form)
        {
            const bool g0 = (s < TT);
            const unsigned sq = (unsigned)(s + 1);
            const size_t rb = (((size_t)(s & 1) * 16 + grp) * 16 + em) * 96 + ej * 6;
            if (g0) {
                u64 W0[6];
                bool ok0 = false;
                int budget = 1 << 17;   // hang-proofing
                do {
#pragma unroll
                    for (int i = 0; i < 6; ++i)
                        W0[i] = __hip_atomic_load(&h0buf[rb + i],
                                                  __ATOMIC_RELAXED, __HIP_MEMORY_SCOPE_AGENT);
                    ok0 = true;
#pragma unroll
                    for (int i = 0; i < 6; ++i) ok0 &= ((unsigned)(W0[i] >> 48) == sq);
                } while (!ok0 && budget-- > 0);

                u64 q[4]; unpack16(W0, q);
                u64* d0 = (u64*)&A0[em][64 + ej * 16];
                u64* d1 = (u64*)&A1[em][ej * 16];
#pragma unroll
                for (int t = 0; t < 4; ++t) { d0[t] = q[t]; d1[t] = q[t]; }
            }
            // drain: publishes/polls retired before next region reuse
            asm volatile("s_waitcnt vmcnt(0)" ::: "memory");
        }
        __syncthreads();   // bar3
    }

    // ---- final: gather h1[T-1] (published step TT, tag TT+1, region TT&1)
    {
        const unsigned sq = (unsigned)(TT + 1);
        const size_t rb = (((size_t)(TT & 1) * 16 + grp) * 16 + em) * 96 + ej * 6;
        u64 W1[6];
        bool ok = false;
        int budget = 1 << 17;
        do {
#pragma unroll
            for (int i = 0; i < 6; ++i)
                W1[i] = __hip_atomic_load(&h1buf[rb + i],
                                          __ATOMIC_RELAXED, __HIP_MEMORY_SCOPE_AGENT);
            ok = true;
#pragma unroll
            for (int i = 0; i < 6; ++i) ok &= ((unsigned)(W1[i] >> 48) == sq);
        } while (!ok && budget-- > 0);
        u64 q[4]; unpack16(W1, q);
        u64* d2 = (u64*)&A1[em][256 + ej * 16];
#pragma unroll
        for (int t = 0; t < 4; ++t) d2[t] = q[t];
    }
    __syncthreads();

    // FC epilogue: A1[:,256..511] holds h1[T-1] (bf16)
    {
        float part = 0.f;
#pragma unroll
        for (int kk = 0; kk < 16; ++kk) {
            int k = ej * 16 + kk;
            part += bf2f(A1[em][256 + k]) * Wfc[k];
        }
        red[em][ej] = part;
    }
    __syncthreads();
    if (chunk == 0 && tid < 16) {
        float sum = bfc[0];
#pragma unroll
        for (int c = 0; c < 16; ++c) sum += red[tid][c];
        out[grp * 16 + tid] = sum;
    }

    // keep ldspad allocated (occupancy cap); never true at runtime
    if (gridDim.x > 100000) { ldspad[tid] = bias0; out[0] = ldspad[255 - tid]; }
}

extern "C" void kernel_launch(void* const* d_in, const int* in_sizes, int n_in,
                              void* d_out, int out_size, void* d_ws, size_t ws_size,
                              hipStream_t stream) {
    (void)in_sizes; (void)n_in; (void)out_size; (void)ws_size;
    const float* x    = (const float*)d_in[0];
    const float* Wih0 = (const float*)d_in[1];
    const float* Whh0 = (const float*)d_in[2];
    const float* bih0 = (const float*)d_in[3];
    const float* bhh0 = (const float*)d_in[4];
    const float* Wih1 = (const float*)d_in[5];
    const float* Whh1 = (const float*)d_in[6];
    const float* bih1 = (const float*)d_in[7];
    const float* bhh1 = (const float*)d_in[8];
    const float* Wfc  = (const float*)d_in[9];
    const float* bfc  = (const float*)d_in[10];

    lstm_fused<<<256, 256, 0, stream>>>(x, Wih0, Whh0, bih0, bhh0,
                                        Wih1, Whh1, bih1, bhh1, Wfc, bfc,
                                        (float*)d_out, (char*)d_ws);
}